// Round 8
// baseline (280.308 us; speedup 1.0000x reference)
//
#include <hip/hip_runtime.h>
#include <math.h>

#define DF 512

__device__ __constant__ int c_lidx[16] = {0,1,1,1,2,2,2,2,2,3,3,3,3,3,3,3};

// K0: fused zero-fill (yacc, out)
__global__ void k_zero(uint4* __restrict__ a, int na, float* __restrict__ out)
{
    int i = blockIdx.x * blockDim.x + threadIdx.x;
    if (i == 0) out[0] = 0.0f;
    if (i < na) a[i] = make_uint4(0, 0, 0, 0);
}

// v[r] = dot(w[r,:], ow) — one wave per row
__global__ __launch_bounds__(512) void k_matvec(const float* __restrict__ w,
                                                const float* __restrict__ ow,
                                                float* __restrict__ v)
{
    int r = blockIdx.x * 8 + (threadIdx.x >> 6);
    int lane = threadIdx.x & 63;
    const float* row = w + (size_t)r * DF;
    float s = 0.0f;
    #pragma unroll
    for (int j = 0; j < 8; j++) s += row[lane + j*64] * ow[lane + j*64];
    #pragma unroll
    for (int off = 32; off > 0; off >>= 1) s += __shfl_xor(s, off, 64);
    if (lane == 0) v[r] = s;
}

// u1[c*16+m] = sum_d tw1[l(m)][c][d]*v[d*16+m]; hb[m] = sum_c lb0[c*16+m]*u1[c*16+m];
// out += N*( (lb1+lb0).ow + ob )
__global__ __launch_bounds__(512) void k_pre2(const float* __restrict__ tw1,
                                              const float* __restrict__ lb1,
                                              const float* __restrict__ lb0,
                                              const float* __restrict__ ow,
                                              const float* __restrict__ ob,
                                              const float* __restrict__ v,
                                              float* __restrict__ u1,
                                              float* __restrict__ hb,
                                              float* __restrict__ out, int N)
{
    __shared__ float vs[DF];
    __shared__ float red[DF];
    __shared__ float us[DF];
    int t = threadIdx.x;
    vs[t] = v[t];
    red[t] = (lb1[t] + lb0[t]) * ow[t];
    __syncthreads();
    int c = t >> 4, m = t & 15, l = c_lidx[m];
    float u = 0.0f;
    #pragma unroll
    for (int d = 0; d < 32; d++) u += tw1[l*1024 + c*32 + d] * vs[d*16 + m];
    u1[t] = u;
    us[t] = u;
    __syncthreads();
    for (int s = 256; s > 0; s >>= 1) {
        if (t < s) red[t] += red[t + s];
        __syncthreads();
    }
    if (t < 16) {
        float s = 0.0f;
        #pragma unroll
        for (int cc = 0; cc < 32; cc++) s += lb0[cc*16 + t] * us[cc*16 + t];
        hb[t] = s;
    }
    if (t == 0) atomicAdd(out, (float)N * (red[0] + ob[0]));
}

// Gt[m][k] = sum_c lw0[k, c*16+m] * u1[c*16+m]
__global__ void k_Gt(const float* __restrict__ lw0, const float* __restrict__ u1,
                     float* __restrict__ Gt)
{
    int g = blockIdx.x * 256 + threadIdx.x;   // 8192
    int k = g >> 4, m = g & 15;
    float s = 0.0f;
    #pragma unroll
    for (int c = 0; c < 32; c++) s += lw0[(size_t)k*DF + c*16 + m] * u1[c*16 + m];
    Gt[m*DF + k] = s;
}

// per-element tables: embdot[a] = emb[a].ow ; hf[a][m] = hb[m] + sum_c emb[a,c*16+m]*u1[c*16+m]
__global__ __launch_bounds__(256) void k_helem(const float* __restrict__ emb,
                                               const float* __restrict__ ow,
                                               const float* __restrict__ u1,
                                               const float* __restrict__ hb,
                                               float* __restrict__ hf,
                                               float* __restrict__ embdot)
{
    __shared__ float r1[256];
    __shared__ float r2[DF];
    int a = blockIdx.x, t = threadIdx.x;
    float e0 = emb[(size_t)a*DF + t];
    float e1 = emb[(size_t)a*DF + t + 256];
    r1[t] = e0*ow[t] + e1*ow[t+256];
    r2[t] = e0*u1[t];
    r2[t+256] = e1*u1[t+256];
    __syncthreads();
    for (int s = 128; s > 0; s >>= 1) {
        if (t < s) r1[t] += r1[t + s];
        __syncthreads();
    }
    if (t < 16) {
        float s = hb[t];
        #pragma unroll
        for (int c = 0; c < 32; c++) s += r2[c*16 + t];
        hf[(size_t)a*16 + t] = s;
    }
    if (t == 0) embdot[a] = r1[0];
}

// per-ELEMENT tensor-product (f32 now): tfe[a, d*16+m] = sum_c emb[a][c*16+m] * tw0[l(m)][c][d]
__global__ __launch_bounds__(256) void k_tf_elem(const float* __restrict__ emb,
                                                 const float* __restrict__ w0,
                                                 float* __restrict__ tfe, int NE)
{
    __shared__ float nf[DF];
    __shared__ float w[4*32*32];
    int a = blockIdx.x;
    int t = threadIdx.x;
    nf[t]       = emb[(size_t)a*DF + t];
    nf[t + 256] = emb[(size_t)a*DF + t + 256];
    for (int i = t; i < 4096; i += 256) w[i] = w0[i];
    __syncthreads();
    #pragma unroll
    for (int rep = 0; rep < 2; rep++) {
        int f = t + rep*256;
        int d = f >> 4, m = f & 15;
        int l = c_lidx[m];
        const float* wl = &w[l*1024 + d];
        float acc = 0.0f;
        #pragma unroll
        for (int c = 0; c < 32; c++) acc += nf[c*16 + m] * wl[c*32];
        tfe[(size_t)a*DF + f] = acc;
    }
}

// T[a][mm][m] = sum_d tfe[a,d*16+mm] * Gt[m][d*16+mm] ; t1[a][mm] = sum_d tfe[a,d*16+mm]*wv0[d*16+mm]
__global__ __launch_bounds__(256) void k_T(const float* __restrict__ tfe,
                                           const float* __restrict__ Gt,
                                           const float* __restrict__ wv0,
                                           float* __restrict__ T,
                                           float* __restrict__ t1)
{
    __shared__ float tf_s[DF];
    int a = blockIdx.x, t = threadIdx.x;
    tf_s[t]       = tfe[(size_t)a*DF + t];
    tf_s[t + 256] = tfe[(size_t)a*DF + t + 256];
    __syncthreads();
    int mm = t >> 4, m = t & 15;
    float s = 0.0f;
    #pragma unroll
    for (int d = 0; d < 32; d++) s = fmaf(tf_s[d*16 + mm], Gt[m*DF + d*16 + mm], s);
    T[(size_t)a*256 + mm*16 + m] = s;
    if (t < 16) {
        float s1 = 0.0f;
        #pragma unroll
        for (int d = 0; d < 32; d++) s1 = fmaf(tf_s[d*16 + t], wv0[d*16 + t], s1);
        t1[(size_t)a*16 + t] = s1;
    }
}

// K1: per-edge SH -> Y[e][16] (edge order, coalesced), aE[e] = an[src[e]]
__global__ void k_sh(const float* __restrict__ pos,
                     const int* __restrict__ src,
                     const int* __restrict__ dst,
                     const int* __restrict__ an,
                     const float* __restrict__ cell,
                     float* __restrict__ Y,
                     int* __restrict__ aE, int E)
{
    int e = blockIdx.x * blockDim.x + threadIdx.x;
    if (e >= E) return;
    int s = src[e], d = dst[e];
    float cx = cell[0], cy = cell[4], cz = cell[8];
    float ex = pos[d*3+0] - pos[s*3+0];
    float ey = pos[d*3+1] - pos[s*3+1];
    float ez = pos[d*3+2] - pos[s*3+2];
    ex -= rintf(ex/cx)*cx;
    ey -= rintf(ey/cy)*cy;
    ez -= rintf(ez/cz)*cz;
    float len = fmaxf(sqrtf(ex*ex + ey*ey + ez*ez), 1e-8f);
    float x = ex/len, y = ey/len, z = ez/len;
    float x2 = x*x, y2 = y*y, z2 = z*z;
    float o[16];
    o[0]  = 0.28209479177387814f;
    o[1]  = 0.4886025119029199f*y;
    o[2]  = 0.4886025119029199f*z;
    o[3]  = 0.4886025119029199f*x;
    o[4]  = 1.0925484305920792f*x*y;
    o[5]  = 1.0925484305920792f*y*z;
    o[6]  = 0.31539156525252005f*(3.0f*z2 - 1.0f);
    o[7]  = 1.0925484305920792f*x*z;
    o[8]  = 0.5462742152960396f*(x2 - y2);
    o[9]  = 0.5900435899266435f*y*(3.0f*x2 - y2);
    o[10] = 2.890611442640554f*x*y*z;
    o[11] = 0.4570457994644658f*y*(5.0f*z2 - 1.0f);
    o[12] = 0.3731763325901154f*z*(5.0f*z2 - 3.0f);
    o[13] = 0.4570457994644658f*x*(5.0f*z2 - 1.0f);
    o[14] = 1.445305721320277f*z*(x2 - y2);
    o[15] = 0.5900435899266435f*x*(x2 - 3.0f*y2);
    float4* yo = (float4*)(Y + (size_t)e*16);
    yo[0] = make_float4(o[0],o[1],o[2],o[3]);
    yo[1] = make_float4(o[4],o[5],o[6],o[7]);
    yo[2] = make_float4(o[8],o[9],o[10],o[11]);
    yo[3] = make_float4(o[12],o[13],o[14],o[15]);
    aE[e] = an[s];
}

// yacc[src[e], m] += Y[e, m]  (one independent atomic per thread)
__global__ void k_yacc(const float* __restrict__ Y, const int* __restrict__ src,
                       float* __restrict__ yacc, int E)
{
    int g = blockIdx.x * blockDim.x + threadIdx.x;
    if (g >= E * 16) return;
    int e = g >> 4, m = g & 15;
    atomicAdd(&yacc[(size_t)src[e]*16 + m], Y[g]);
}

// K_final: edge-parallel energy (16 lanes per edge) + node tail groups.
// edge e: s = sum_m yacc[dst_e, m] * (sum_mm Y[e,mm]*T[aE,mm,m]) + sum_mm Y[e,mm]*t1[aE,mm]
// node n: s = embdot[an[n]] + sum_m hf[an[n],m]*yacc[n,m]
__global__ __launch_bounds__(256) void k_energy(const float* __restrict__ Y,
                                                const int* __restrict__ dst,
                                                const int* __restrict__ aE,
                                                const int* __restrict__ an,
                                                const float* __restrict__ yacc,
                                                const float* __restrict__ T,
                                                const float* __restrict__ t1,
                                                const float* __restrict__ hf,
                                                const float* __restrict__ embdot,
                                                float* __restrict__ out, int E, int N)
{
    int gid = (blockIdx.x * 256 + threadIdx.x) >> 4;
    int sub = threadIdx.x & 15;
    float s = 0.0f;
    if (gid < E) {
        int a = aE[gid];
        int d = dst[gid];
        float myY = Y[(size_t)gid*16 + sub];
        const float* Ta = T + (size_t)a*256;
        float q = 0.0f;
        int base = threadIdx.x & 48;  // 16-group base within wave
        #pragma unroll
        for (int mm = 0; mm < 16; mm++) {
            float yv = __shfl(myY, base + mm, 64);
            q = fmaf(yv, Ta[mm*16 + sub], q);
        }
        s = q * yacc[(size_t)d*16 + sub] + myY * t1[(size_t)a*16 + sub];
    } else if (gid < E + N) {
        int n = gid - E;
        int a = an[n];
        s = hf[(size_t)a*16 + sub] * yacc[(size_t)n*16 + sub];
        if (sub == 0) s += embdot[a];
    }
    s += __shfl_xor(s, 1, 64);
    s += __shfl_xor(s, 2, 64);
    s += __shfl_xor(s, 4, 64);
    s += __shfl_xor(s, 8, 64);
    float sw = (sub == 0) ? s : 0.0f;
    sw += __shfl_xor(sw, 16, 64);
    sw += __shfl_xor(sw, 32, 64);
    __shared__ float wred[4];
    int lane = threadIdx.x & 63, w = threadIdx.x >> 6;
    if (lane == 0) wred[w] = sw;
    __syncthreads();
    if (threadIdx.x == 0) atomicAdd(out, wred[0] + wred[1] + wred[2] + wred[3]);
}

extern "C" void kernel_launch(void* const* d_in, const int* in_sizes, int n_in,
                              void* d_out, int out_size, void* d_ws, size_t ws_size,
                              hipStream_t stream)
{
    const float* pos  = (const float*)d_in[0];
    const float* cell = (const float*)d_in[1];
    const int*   an   = (const int*)d_in[2];
    const int*   ei   = (const int*)d_in[3];
    const float* emb  = (const float*)d_in[4];
    const float* tw0  = (const float*)d_in[5];
    const float* lw0  = (const float*)d_in[6];
    const float* lb0  = (const float*)d_in[7];
    const float* tw1  = (const float*)d_in[8];
    const float* lw1  = (const float*)d_in[9];
    const float* lb1  = (const float*)d_in[10];
    const float* ow   = (const float*)d_in[11];
    const float* ob   = (const float*)d_in[12];
    int N  = in_sizes[0] / 3;
    int E  = in_sizes[3] / 2;
    int NE = in_sizes[4] / DF;   // 89 elements
    const int* src = ei;
    const int* dst = ei + E;

    char* ws = (char*)d_ws;
    size_t off = 0;
    auto alloc = [&](size_t bytes) { void* p = ws + off; off += (bytes + 255) / 256 * 256; return p; };

    float* Y      = (float*)alloc((size_t)E * 16 * 4);
    int*   aE     = (int*)alloc((size_t)E * 4);
    float* tfe    = (float*)alloc((size_t)NE * DF * 4);
    float* u1     = (float*)alloc(DF * 4);
    float* vtmp   = (float*)alloc(DF * 4);
    float* wv0    = (float*)alloc(DF * 4);
    float* hb     = (float*)alloc(16 * 4);
    float* Gt     = (float*)alloc(16 * DF * 4);
    float* T      = (float*)alloc((size_t)NE * 256 * 4);
    float* t1     = (float*)alloc((size_t)NE * 16 * 4);
    float* hf     = (float*)alloc((size_t)NE * 16 * 4);
    float* embdot = (float*)alloc((size_t)NE * 4);
    float* yacc   = (float*)alloc((size_t)N * 16 * 4);

    float* out = (float*)d_out;

    int na = (N * 64) / 16;
    k_zero<<<(na + 255) / 256, 256, 0, stream>>>((uint4*)yacc, na, out);

    k_matvec<<<DF / 8, 512, 0, stream>>>(lw1, ow, vtmp);
    k_matvec<<<DF / 8, 512, 0, stream>>>(lw0, ow, wv0);
    k_pre2<<<1, 512, 0, stream>>>(tw1, lb1, lb0, ow, ob, vtmp, u1, hb, out, N);
    k_Gt<<<(16 * DF) / 256, 256, 0, stream>>>(lw0, u1, Gt);
    k_helem<<<NE, 256, 0, stream>>>(emb, ow, u1, hb, hf, embdot);
    k_tf_elem<<<NE, 256, 0, stream>>>(emb, tw0, tfe, NE);
    k_T<<<NE, 256, 0, stream>>>(tfe, Gt, wv0, T, t1);
    k_sh<<<(E + 255) / 256, 256, 0, stream>>>(pos, src, dst, an, cell, Y, aE, E);
    k_yacc<<<(E * 16 + 255) / 256, 256, 0, stream>>>(Y, src, yacc, E);
    int ngroups = E + N;
    k_energy<<<((size_t)ngroups * 16 + 255) / 256, 256, 0, stream>>>(
        Y, dst, aE, an, yacc, T, t1, hf, embdot, out, E, N);
}

// Round 9
// 99.089 us; speedup vs baseline: 2.8289x; 2.8289x over previous
//
#include <hip/hip_runtime.h>
#include <math.h>

#define DF 512

__device__ __constant__ int c_lidx[16] = {0,1,1,1,2,2,2,2,2,3,3,3,3,3,3,3};

// K0: fused zero-fill (yacc, out)
__global__ void k_zero(uint4* __restrict__ a, int na, float* __restrict__ out)
{
    int i = blockIdx.x * blockDim.x + threadIdx.x;
    if (i == 0) out[0] = 0.0f;
    if (i < na) a[i] = make_uint4(0, 0, 0, 0);
}

// v[r] = dot(w[r,:], ow) — one wave per row
__global__ __launch_bounds__(512) void k_matvec(const float* __restrict__ w,
                                                const float* __restrict__ ow,
                                                float* __restrict__ v)
{
    int r = blockIdx.x * 8 + (threadIdx.x >> 6);
    int lane = threadIdx.x & 63;
    const float* row = w + (size_t)r * DF;
    float s = 0.0f;
    #pragma unroll
    for (int j = 0; j < 8; j++) s += row[lane + j*64] * ow[lane + j*64];
    #pragma unroll
    for (int off = 32; off > 0; off >>= 1) s += __shfl_xor(s, off, 64);
    if (lane == 0) v[r] = s;
}

// u1[c*16+m] = sum_d tw1[l(m)][c][d]*v[d*16+m]; hb[m] = sum_c lb0[c*16+m]*u1[c*16+m];
// out += N*( (lb1+lb0).ow + ob )
__global__ __launch_bounds__(512) void k_pre2(const float* __restrict__ tw1,
                                              const float* __restrict__ lb1,
                                              const float* __restrict__ lb0,
                                              const float* __restrict__ ow,
                                              const float* __restrict__ ob,
                                              const float* __restrict__ v,
                                              float* __restrict__ u1,
                                              float* __restrict__ hb,
                                              float* __restrict__ out, int N)
{
    __shared__ float vs[DF];
    __shared__ float red[DF];
    __shared__ float us[DF];
    int t = threadIdx.x;
    vs[t] = v[t];
    red[t] = (lb1[t] + lb0[t]) * ow[t];
    __syncthreads();
    int c = t >> 4, m = t & 15, l = c_lidx[m];
    float u = 0.0f;
    #pragma unroll
    for (int d = 0; d < 32; d++) u += tw1[l*1024 + c*32 + d] * vs[d*16 + m];
    u1[t] = u;
    us[t] = u;
    __syncthreads();
    for (int s = 256; s > 0; s >>= 1) {
        if (t < s) red[t] += red[t + s];
        __syncthreads();
    }
    if (t < 16) {
        float s = 0.0f;
        #pragma unroll
        for (int cc = 0; cc < 32; cc++) s += lb0[cc*16 + t] * us[cc*16 + t];
        hb[t] = s;
    }
    if (t == 0) atomicAdd(out, (float)N * (red[0] + ob[0]));
}

// Gt[m][k] = sum_c lw0[k, c*16+m] * u1[c*16+m]
__global__ void k_Gt(const float* __restrict__ lw0, const float* __restrict__ u1,
                     float* __restrict__ Gt)
{
    int g = blockIdx.x * 256 + threadIdx.x;   // 8192
    int k = g >> 4, m = g & 15;
    float s = 0.0f;
    #pragma unroll
    for (int c = 0; c < 32; c++) s += lw0[(size_t)k*DF + c*16 + m] * u1[c*16 + m];
    Gt[m*DF + k] = s;
}

// per-element tables: embdot[a] = emb[a].ow ; hf[a][m] = hb[m] + sum_c emb[a,c*16+m]*u1[c*16+m]
__global__ __launch_bounds__(256) void k_helem(const float* __restrict__ emb,
                                               const float* __restrict__ ow,
                                               const float* __restrict__ u1,
                                               const float* __restrict__ hb,
                                               float* __restrict__ hf,
                                               float* __restrict__ embdot)
{
    __shared__ float r1[256];
    __shared__ float r2[DF];
    int a = blockIdx.x, t = threadIdx.x;
    float e0 = emb[(size_t)a*DF + t];
    float e1 = emb[(size_t)a*DF + t + 256];
    r1[t] = e0*ow[t] + e1*ow[t+256];
    r2[t] = e0*u1[t];
    r2[t+256] = e1*u1[t+256];
    __syncthreads();
    for (int s = 128; s > 0; s >>= 1) {
        if (t < s) r1[t] += r1[t + s];
        __syncthreads();
    }
    if (t < 16) {
        float s = hb[t];
        #pragma unroll
        for (int c = 0; c < 32; c++) s += r2[c*16 + t];
        hf[(size_t)a*16 + t] = s;
    }
    if (t == 0) embdot[a] = r1[0];
}

// per-ELEMENT tensor-product (f32): tfe[a, d*16+m] = sum_c emb[a][c*16+m] * tw0[l(m)][c][d]
__global__ __launch_bounds__(256) void k_tf_elem(const float* __restrict__ emb,
                                                 const float* __restrict__ w0,
                                                 float* __restrict__ tfe, int NE)
{
    __shared__ float nf[DF];
    __shared__ float w[4*32*32];
    int a = blockIdx.x;
    int t = threadIdx.x;
    nf[t]       = emb[(size_t)a*DF + t];
    nf[t + 256] = emb[(size_t)a*DF + t + 256];
    for (int i = t; i < 4096; i += 256) w[i] = w0[i];
    __syncthreads();
    #pragma unroll
    for (int rep = 0; rep < 2; rep++) {
        int f = t + rep*256;
        int d = f >> 4, m = f & 15;
        int l = c_lidx[m];
        const float* wl = &w[l*1024 + d];
        float acc = 0.0f;
        #pragma unroll
        for (int c = 0; c < 32; c++) acc += nf[c*16 + m] * wl[c*32];
        tfe[(size_t)a*DF + f] = acc;
    }
}

// T[a][mm][m] = sum_d tfe[a,d*16+mm] * Gt[m][d*16+mm] ; t1[a][mm] = sum_d tfe[a,d*16+mm]*wv0[d*16+mm]
__global__ __launch_bounds__(256) void k_T(const float* __restrict__ tfe,
                                           const float* __restrict__ Gt,
                                           const float* __restrict__ wv0,
                                           float* __restrict__ T,
                                           float* __restrict__ t1)
{
    __shared__ float tf_s[DF];
    int a = blockIdx.x, t = threadIdx.x;
    tf_s[t]       = tfe[(size_t)a*DF + t];
    tf_s[t + 256] = tfe[(size_t)a*DF + t + 256];
    __syncthreads();
    int mm = t >> 4, m = t & 15;
    float s = 0.0f;
    #pragma unroll
    for (int d = 0; d < 32; d++) s = fmaf(tf_s[d*16 + mm], Gt[m*DF + d*16 + mm], s);
    T[(size_t)a*256 + mm*16 + m] = s;
    if (t < 16) {
        float s1 = 0.0f;
        #pragma unroll
        for (int d = 0; d < 32; d++) s1 = fmaf(tf_s[d*16 + t], wv0[d*16 + t], s1);
        t1[(size_t)a*16 + t] = s1;
    }
}

// K1: per-edge SH -> Y[e][16] (edge order, coalesced), aE[e] = an[src[e]]
__global__ void k_sh(const float* __restrict__ pos,
                     const int* __restrict__ src,
                     const int* __restrict__ dst,
                     const int* __restrict__ an,
                     const float* __restrict__ cell,
                     float* __restrict__ Y,
                     int* __restrict__ aE, int E)
{
    int e = blockIdx.x * blockDim.x + threadIdx.x;
    if (e >= E) return;
    int s = src[e], d = dst[e];
    float cx = cell[0], cy = cell[4], cz = cell[8];
    float ex = pos[d*3+0] - pos[s*3+0];
    float ey = pos[d*3+1] - pos[s*3+1];
    float ez = pos[d*3+2] - pos[s*3+2];
    ex -= rintf(ex/cx)*cx;
    ey -= rintf(ey/cy)*cy;
    ez -= rintf(ez/cz)*cz;
    float len = fmaxf(sqrtf(ex*ex + ey*ey + ez*ez), 1e-8f);
    float x = ex/len, y = ey/len, z = ez/len;
    float x2 = x*x, y2 = y*y, z2 = z*z;
    float o[16];
    o[0]  = 0.28209479177387814f;
    o[1]  = 0.4886025119029199f*y;
    o[2]  = 0.4886025119029199f*z;
    o[3]  = 0.4886025119029199f*x;
    o[4]  = 1.0925484305920792f*x*y;
    o[5]  = 1.0925484305920792f*y*z;
    o[6]  = 0.31539156525252005f*(3.0f*z2 - 1.0f);
    o[7]  = 1.0925484305920792f*x*z;
    o[8]  = 0.5462742152960396f*(x2 - y2);
    o[9]  = 0.5900435899266435f*y*(3.0f*x2 - y2);
    o[10] = 2.890611442640554f*x*y*z;
    o[11] = 0.4570457994644658f*y*(5.0f*z2 - 1.0f);
    o[12] = 0.3731763325901154f*z*(5.0f*z2 - 3.0f);
    o[13] = 0.4570457994644658f*x*(5.0f*z2 - 1.0f);
    o[14] = 1.445305721320277f*z*(x2 - y2);
    o[15] = 0.5900435899266435f*x*(x2 - 3.0f*y2);
    float4* yo = (float4*)(Y + (size_t)e*16);
    yo[0] = make_float4(o[0],o[1],o[2],o[3]);
    yo[1] = make_float4(o[4],o[5],o[6],o[7]);
    yo[2] = make_float4(o[8],o[9],o[10],o[11]);
    yo[3] = make_float4(o[12],o[13],o[14],o[15]);
    aE[e] = an[s];
}

// yacc[src[e], m] += Y[e, m]  (one independent atomic per thread)
__global__ void k_yacc(const float* __restrict__ Y, const int* __restrict__ src,
                       float* __restrict__ yacc, int E)
{
    int g = blockIdx.x * blockDim.x + threadIdx.x;
    if (g >= E * 16) return;
    int e = g >> 4, m = g & 15;
    atomicAdd(&yacc[(size_t)src[e]*16 + m], Y[g]);
}

// K_final v2: ONE EDGE PER LANE, no cross-lane ops in hot loop.
// edge e: s = sum_mm Y[e,mm] * ( T[aE[e]][mm][:] . yacc[dst_e][:] + t1[aE[e]][mm] )
// node n: s = embdot[an[n]] + sum_m hf[an[n],m]*yacc[n,m]
__global__ __launch_bounds__(256) void k_energy(const float* __restrict__ Y,
                                                const int* __restrict__ dst,
                                                const int* __restrict__ aE,
                                                const int* __restrict__ an,
                                                const float* __restrict__ yacc,
                                                const float* __restrict__ T,
                                                const float* __restrict__ t1,
                                                const float* __restrict__ hf,
                                                const float* __restrict__ embdot,
                                                float* __restrict__ out, int E, int N)
{
    int i = blockIdx.x * 256 + threadIdx.x;
    float s = 0.0f;
    if (i < E) {
        int a = aE[i];
        int d = dst[i];
        const float4* yp = (const float4*)(Y + (size_t)i*16);
        float4 Y0 = yp[0], Y1 = yp[1], Y2 = yp[2], Y3 = yp[3];
        const float4* dp = (const float4*)(yacc + (size_t)d*16);
        float4 D0 = dp[0], D1 = dp[1], D2 = dp[2], D3 = dp[3];
        const float4* Ta = (const float4*)(T + (size_t)a*256);
        const float4* tp = (const float4*)(t1 + (size_t)a*16);
        float4 t0 = tp[0], t14 = tp[1], t28 = tp[2], t3c = tp[3];
        float ov[16] = {Y0.x,Y0.y,Y0.z,Y0.w, Y1.x,Y1.y,Y1.z,Y1.w,
                        Y2.x,Y2.y,Y2.z,Y2.w, Y3.x,Y3.y,Y3.z,Y3.w};
        float tv[16] = {t0.x,t0.y,t0.z,t0.w, t14.x,t14.y,t14.z,t14.w,
                        t28.x,t28.y,t28.z,t28.w, t3c.x,t3c.y,t3c.z,t3c.w};
        #pragma unroll
        for (int mm = 0; mm < 16; mm++) {
            float4 r0 = Ta[mm*4+0], r1 = Ta[mm*4+1], r2 = Ta[mm*4+2], r3 = Ta[mm*4+3];
            float dotv = r0.x*D0.x + r0.y*D0.y + r0.z*D0.z + r0.w*D0.w
                       + r1.x*D1.x + r1.y*D1.y + r1.z*D1.z + r1.w*D1.w
                       + r2.x*D2.x + r2.y*D2.y + r2.z*D2.z + r2.w*D2.w
                       + r3.x*D3.x + r3.y*D3.y + r3.z*D3.z + r3.w*D3.w;
            s = fmaf(ov[mm], dotv + tv[mm], s);
        }
    } else if (i < E + N) {
        int n = i - E;
        int a = an[n];
        const float4* hp = (const float4*)(hf + (size_t)a*16);
        float4 H0 = hp[0], H1 = hp[1], H2 = hp[2], H3 = hp[3];
        const float4* vp = (const float4*)(yacc + (size_t)n*16);
        float4 V0 = vp[0], V1 = vp[1], V2 = vp[2], V3 = vp[3];
        s = embdot[a]
          + H0.x*V0.x + H0.y*V0.y + H0.z*V0.z + H0.w*V0.w
          + H1.x*V1.x + H1.y*V1.y + H1.z*V1.z + H1.w*V1.w
          + H2.x*V2.x + H2.y*V2.y + H2.z*V2.z + H2.w*V2.w
          + H3.x*V3.x + H3.y*V3.y + H3.z*V3.z + H3.w*V3.w;
    }
    #pragma unroll
    for (int off = 32; off > 0; off >>= 1) s += __shfl_xor(s, off, 64);
    __shared__ float wred[4];
    int lane = threadIdx.x & 63, w = threadIdx.x >> 6;
    if (lane == 0) wred[w] = s;
    __syncthreads();
    if (threadIdx.x == 0) atomicAdd(out, wred[0] + wred[1] + wred[2] + wred[3]);
}

extern "C" void kernel_launch(void* const* d_in, const int* in_sizes, int n_in,
                              void* d_out, int out_size, void* d_ws, size_t ws_size,
                              hipStream_t stream)
{
    const float* pos  = (const float*)d_in[0];
    const float* cell = (const float*)d_in[1];
    const int*   an   = (const int*)d_in[2];
    const int*   ei   = (const int*)d_in[3];
    const float* emb  = (const float*)d_in[4];
    const float* tw0  = (const float*)d_in[5];
    const float* lw0  = (const float*)d_in[6];
    const float* lb0  = (const float*)d_in[7];
    const float* tw1  = (const float*)d_in[8];
    const float* lw1  = (const float*)d_in[9];
    const float* lb1  = (const float*)d_in[10];
    const float* ow   = (const float*)d_in[11];
    const float* ob   = (const float*)d_in[12];
    int N  = in_sizes[0] / 3;
    int E  = in_sizes[3] / 2;
    int NE = in_sizes[4] / DF;   // 89 elements
    const int* src = ei;
    const int* dst = ei + E;

    char* ws = (char*)d_ws;
    size_t off = 0;
    auto alloc = [&](size_t bytes) { void* p = ws + off; off += (bytes + 255) / 256 * 256; return p; };

    float* Y      = (float*)alloc((size_t)E * 16 * 4);
    int*   aE     = (int*)alloc((size_t)E * 4);
    float* tfe    = (float*)alloc((size_t)NE * DF * 4);
    float* u1     = (float*)alloc(DF * 4);
    float* vtmp   = (float*)alloc(DF * 4);
    float* wv0    = (float*)alloc(DF * 4);
    float* hb     = (float*)alloc(16 * 4);
    float* Gt     = (float*)alloc(16 * DF * 4);
    float* T      = (float*)alloc((size_t)NE * 256 * 4);
    float* t1     = (float*)alloc((size_t)NE * 16 * 4);
    float* hf     = (float*)alloc((size_t)NE * 16 * 4);
    float* embdot = (float*)alloc((size_t)NE * 4);
    float* yacc   = (float*)alloc((size_t)N * 16 * 4);

    float* out = (float*)d_out;

    int na = (N * 64) / 16;
    k_zero<<<(na + 255) / 256, 256, 0, stream>>>((uint4*)yacc, na, out);

    k_matvec<<<DF / 8, 512, 0, stream>>>(lw1, ow, vtmp);
    k_matvec<<<DF / 8, 512, 0, stream>>>(lw0, ow, wv0);
    k_pre2<<<1, 512, 0, stream>>>(tw1, lb1, lb0, ow, ob, vtmp, u1, hb, out, N);
    k_Gt<<<(16 * DF) / 256, 256, 0, stream>>>(lw0, u1, Gt);
    k_helem<<<NE, 256, 0, stream>>>(emb, ow, u1, hb, hf, embdot);
    k_tf_elem<<<NE, 256, 0, stream>>>(emb, tw0, tfe, NE);
    k_T<<<NE, 256, 0, stream>>>(tfe, Gt, wv0, T, t1);
    k_sh<<<(E + 255) / 256, 256, 0, stream>>>(pos, src, dst, an, cell, Y, aE, E);
    k_yacc<<<(E * 16 + 255) / 256, 256, 0, stream>>>(Y, src, yacc, E);
    int nthreads = E + N;
    k_energy<<<(nthreads + 255) / 256, 256, 0, stream>>>(
        Y, dst, aE, an, yacc, T, t1, hf, embdot, out, E, N);
}

// Round 10
// 76.172 us; speedup vs baseline: 3.6799x; 1.3009x over previous
//
#include <hip/hip_runtime.h>
#include <math.h>

#define DF 512

__device__ __constant__ int c_lidx[16] = {0,1,1,1,2,2,2,2,2,3,3,3,3,3,3,3};

__device__ inline void sh_eval(float x, float y, float z, float* o)
{
    float x2 = x*x, y2 = y*y, z2 = z*z;
    o[0]  = 0.28209479177387814f;
    o[1]  = 0.4886025119029199f*y;
    o[2]  = 0.4886025119029199f*z;
    o[3]  = 0.4886025119029199f*x;
    o[4]  = 1.0925484305920792f*x*y;
    o[5]  = 1.0925484305920792f*y*z;
    o[6]  = 0.31539156525252005f*(3.0f*z2 - 1.0f);
    o[7]  = 1.0925484305920792f*x*z;
    o[8]  = 0.5462742152960396f*(x2 - y2);
    o[9]  = 0.5900435899266435f*y*(3.0f*x2 - y2);
    o[10] = 2.890611442640554f*x*y*z;
    o[11] = 0.4570457994644658f*y*(5.0f*z2 - 1.0f);
    o[12] = 0.3731763325901154f*z*(5.0f*z2 - 3.0f);
    o[13] = 0.4570457994644658f*x*(5.0f*z2 - 1.0f);
    o[14] = 1.445305721320277f*z*(x2 - y2);
    o[15] = 0.5900435899266435f*x*(x2 - 3.0f*y2);
}

__device__ inline void edge_dir(const float* __restrict__ pos, int s, int d,
                                float cx, float cy, float cz,
                                float& x, float& y, float& z)
{
    float ex = pos[d*3+0] - pos[s*3+0];
    float ey = pos[d*3+1] - pos[s*3+1];
    float ez = pos[d*3+2] - pos[s*3+2];
    ex -= rintf(ex/cx)*cx;
    ey -= rintf(ey/cy)*cy;
    ez -= rintf(ez/cz)*cz;
    float len = fmaxf(sqrtf(ex*ex + ey*ey + ez*ez), 1e-8f);
    x = ex/len; y = ey/len; z = ez/len;
}

// K_A: layered fused setup — blocks [0,64): vtmp=lw1@ow; [64,128): wv0=lw0@ow;
// [128,217): tfe per element; [217,377): zero yacc (+ out)
__global__ __launch_bounds__(512) void k_setup(const float* __restrict__ lw1,
                                               const float* __restrict__ lw0,
                                               const float* __restrict__ ow,
                                               const float* __restrict__ emb,
                                               const float* __restrict__ tw0,
                                               float* __restrict__ vtmp,
                                               float* __restrict__ wv0,
                                               float* __restrict__ tfe,
                                               uint4* __restrict__ yacc4, int nyacc4,
                                               float* __restrict__ out, int NE)
{
    int b = blockIdx.x, t = threadIdx.x;
    if (b < 128) {
        const float* w = (b < 64) ? lw1 : lw0;
        float* v = (b < 64) ? vtmp : wv0;
        int bb = b & 63;
        int r = bb*8 + (t >> 6);
        int lane = t & 63;
        const float* row = w + (size_t)r * DF;
        float s = 0.0f;
        #pragma unroll
        for (int j = 0; j < 8; j++) s += row[lane + j*64] * ow[lane + j*64];
        #pragma unroll
        for (int off = 32; off > 0; off >>= 1) s += __shfl_xor(s, off, 64);
        if (lane == 0) v[r] = s;
    } else if (b < 128 + NE) {
        __shared__ float nf[DF];
        __shared__ float w[4*32*32];
        int a = b - 128;
        nf[t] = emb[(size_t)a*DF + t];
        for (int i = t; i < 4096; i += 512) w[i] = tw0[i];
        __syncthreads();
        int d = t >> 4, m = t & 15;
        int l = c_lidx[m];
        const float* wl = &w[l*1024 + d];
        float acc = 0.0f;
        #pragma unroll
        for (int c = 0; c < 32; c++) acc += nf[c*16 + m] * wl[c*32];
        tfe[(size_t)a*DF + t] = acc;
    } else {
        int i = (b - 128 - NE)*512 + t;
        if (i < nyacc4) yacc4[i] = make_uint4(0,0,0,0);
        if (i == 0) out[0] = 0.0f;
    }
}

// K_B: u1, hb, constant bias energy (1 block)
__global__ __launch_bounds__(512) void k_pre2(const float* __restrict__ tw1,
                                              const float* __restrict__ lb1,
                                              const float* __restrict__ lb0,
                                              const float* __restrict__ ow,
                                              const float* __restrict__ ob,
                                              const float* __restrict__ v,
                                              float* __restrict__ u1,
                                              float* __restrict__ hb,
                                              float* __restrict__ out, int N)
{
    __shared__ float vs[DF];
    __shared__ float red[DF];
    __shared__ float us[DF];
    int t = threadIdx.x;
    vs[t] = v[t];
    red[t] = (lb1[t] + lb0[t]) * ow[t];
    __syncthreads();
    int c = t >> 4, m = t & 15, l = c_lidx[m];
    float u = 0.0f;
    #pragma unroll
    for (int d = 0; d < 32; d++) u += tw1[l*1024 + c*32 + d] * vs[d*16 + m];
    u1[t] = u;
    us[t] = u;
    __syncthreads();
    for (int s = 256; s > 0; s >>= 1) {
        if (t < s) red[t] += red[t + s];
        __syncthreads();
    }
    if (t < 16) {
        float s = 0.0f;
        #pragma unroll
        for (int cc = 0; cc < 32; cc++) s += lb0[cc*16 + t] * us[cc*16 + t];
        hb[t] = s;
    }
    if (t == 0) atomicAdd(out, (float)N * (red[0] + ob[0]));
}

// K_C: blocks [0,32): Gt ; blocks [32,32+NE): helem
__global__ __launch_bounds__(256) void k_gt_helem(const float* __restrict__ lw0,
                                                  const float* __restrict__ u1,
                                                  const float* __restrict__ emb,
                                                  const float* __restrict__ ow,
                                                  const float* __restrict__ hb,
                                                  float* __restrict__ Gt,
                                                  float* __restrict__ hf,
                                                  float* __restrict__ embdot)
{
    int b = blockIdx.x, t = threadIdx.x;
    if (b < 32) {
        int g = b*256 + t;
        int k = g >> 4, m = g & 15;
        float s = 0.0f;
        #pragma unroll
        for (int c = 0; c < 32; c++) s += lw0[(size_t)k*DF + c*16 + m] * u1[c*16 + m];
        Gt[m*DF + k] = s;
    } else {
        __shared__ float r1[256];
        __shared__ float r2[DF];
        int a = b - 32;
        float e0 = emb[(size_t)a*DF + t];
        float e1 = emb[(size_t)a*DF + t + 256];
        r1[t] = e0*ow[t] + e1*ow[t+256];
        r2[t] = e0*u1[t];
        r2[t+256] = e1*u1[t+256];
        __syncthreads();
        for (int s = 128; s > 0; s >>= 1) {
            if (t < s) r1[t] += r1[t + s];
            __syncthreads();
        }
        if (t < 16) {
            float s = hb[t];
            #pragma unroll
            for (int c = 0; c < 32; c++) s += r2[c*16 + t];
            hf[(size_t)a*16 + t] = s;
        }
        if (t == 0) embdot[a] = r1[0];
    }
}

// K_D: T[a][mm][m], t1[a][mm]
__global__ __launch_bounds__(256) void k_T(const float* __restrict__ tfe,
                                           const float* __restrict__ Gt,
                                           const float* __restrict__ wv0,
                                           float* __restrict__ T,
                                           float* __restrict__ t1)
{
    __shared__ float tf_s[DF];
    int a = blockIdx.x, t = threadIdx.x;
    tf_s[t]       = tfe[(size_t)a*DF + t];
    tf_s[t + 256] = tfe[(size_t)a*DF + t + 256];
    __syncthreads();
    int mm = t >> 4, m = t & 15;
    float s = 0.0f;
    #pragma unroll
    for (int d = 0; d < 32; d++) s = fmaf(tf_s[d*16 + mm], Gt[m*DF + d*16 + mm], s);
    T[(size_t)a*256 + mm*16 + m] = s;
    if (t < 16) {
        float s1 = 0.0f;
        #pragma unroll
        for (int d = 0; d < 32; d++) s1 = fmaf(tf_s[d*16 + t], wv0[d*16 + t], s1);
        t1[(size_t)a*16 + t] = s1;
    }
}

// K_E: SH compute + yacc atomics, LDS-staged (no Y materialization).
__global__ __launch_bounds__(256) void k_sh_yacc(const float* __restrict__ pos,
                                                 const int* __restrict__ src,
                                                 const int* __restrict__ dst,
                                                 const float* __restrict__ cell,
                                                 float* __restrict__ yacc, int E)
{
    __shared__ float Yl[256][17];
    __shared__ int sAl[256];
    int b = blockIdx.x, t = threadIdx.x;
    int e = b*256 + t;
    float cx = cell[0], cy = cell[4], cz = cell[8];
    if (e < E) {
        int s = src[e], d = dst[e];
        float x, y, z;
        edge_dir(pos, s, d, cx, cy, cz, x, y, z);
        float o[16];
        sh_eval(x, y, z, o);
        #pragma unroll
        for (int j = 0; j < 16; j++) Yl[t][j] = o[j];
        sAl[t] = s;
    }
    __syncthreads();
    int lastvalid = min(256, E - b*256);   // edges valid in this block
    #pragma unroll
    for (int j = 0; j < 16; j++) {
        int idx = j*256 + t;
        int el = idx >> 4, m = idx & 15;
        if (el < lastvalid)
            atomicAdd(&yacc[(size_t)sAl[el]*16 + m], Yl[el][m]);
    }
}

// K_F: edge-parallel energy with SH recompute (one edge per lane) + node tail.
__global__ __launch_bounds__(256) void k_energy(const float* __restrict__ pos,
                                                const int* __restrict__ src,
                                                const int* __restrict__ dst,
                                                const int* __restrict__ an,
                                                const float* __restrict__ cell,
                                                const float* __restrict__ yacc,
                                                const float* __restrict__ T,
                                                const float* __restrict__ t1,
                                                const float* __restrict__ hf,
                                                const float* __restrict__ embdot,
                                                float* __restrict__ out, int E, int N)
{
    int i = blockIdx.x * 256 + threadIdx.x;
    float s = 0.0f;
    if (i < E) {
        int sn = src[i], d = dst[i];
        int a = an[sn];
        float x, y, z;
        edge_dir(pos, sn, d, cell[0], cell[4], cell[8], x, y, z);
        float ov[16];
        sh_eval(x, y, z, ov);
        const float4* dp = (const float4*)(yacc + (size_t)d*16);
        float4 D0 = dp[0], D1 = dp[1], D2 = dp[2], D3 = dp[3];
        const float4* Ta = (const float4*)(T + (size_t)a*256);
        const float4* tp = (const float4*)(t1 + (size_t)a*16);
        float4 t0 = tp[0], t14 = tp[1], t28 = tp[2], t3c = tp[3];
        float tv[16] = {t0.x,t0.y,t0.z,t0.w, t14.x,t14.y,t14.z,t14.w,
                        t28.x,t28.y,t28.z,t28.w, t3c.x,t3c.y,t3c.z,t3c.w};
        #pragma unroll
        for (int mm = 0; mm < 16; mm++) {
            float4 r0 = Ta[mm*4+0], r1 = Ta[mm*4+1], r2 = Ta[mm*4+2], r3 = Ta[mm*4+3];
            float dotv = r0.x*D0.x + r0.y*D0.y + r0.z*D0.z + r0.w*D0.w
                       + r1.x*D1.x + r1.y*D1.y + r1.z*D1.z + r1.w*D1.w
                       + r2.x*D2.x + r2.y*D2.y + r2.z*D2.z + r2.w*D2.w
                       + r3.x*D3.x + r3.y*D3.y + r3.z*D3.z + r3.w*D3.w;
            s = fmaf(ov[mm], dotv + tv[mm], s);
        }
    } else if (i < E + N) {
        int n = i - E;
        int a = an[n];
        const float4* hp = (const float4*)(hf + (size_t)a*16);
        float4 H0 = hp[0], H1 = hp[1], H2 = hp[2], H3 = hp[3];
        const float4* vp = (const float4*)(yacc + (size_t)n*16);
        float4 V0 = vp[0], V1 = vp[1], V2 = vp[2], V3 = vp[3];
        s = embdot[a]
          + H0.x*V0.x + H0.y*V0.y + H0.z*V0.z + H0.w*V0.w
          + H1.x*V1.x + H1.y*V1.y + H1.z*V1.z + H1.w*V1.w
          + H2.x*V2.x + H2.y*V2.y + H2.z*V2.z + H2.w*V2.w
          + H3.x*V3.x + H3.y*V3.y + H3.z*V3.z + H3.w*V3.w;
    }
    #pragma unroll
    for (int off = 32; off > 0; off >>= 1) s += __shfl_xor(s, off, 64);
    __shared__ float wred[4];
    int lane = threadIdx.x & 63, w = threadIdx.x >> 6;
    if (lane == 0) wred[w] = s;
    __syncthreads();
    if (threadIdx.x == 0) atomicAdd(out, wred[0] + wred[1] + wred[2] + wred[3]);
}

extern "C" void kernel_launch(void* const* d_in, const int* in_sizes, int n_in,
                              void* d_out, int out_size, void* d_ws, size_t ws_size,
                              hipStream_t stream)
{
    const float* pos  = (const float*)d_in[0];
    const float* cell = (const float*)d_in[1];
    const int*   an   = (const int*)d_in[2];
    const int*   ei   = (const int*)d_in[3];
    const float* emb  = (const float*)d_in[4];
    const float* tw0  = (const float*)d_in[5];
    const float* lw0  = (const float*)d_in[6];
    const float* lb0  = (const float*)d_in[7];
    const float* tw1  = (const float*)d_in[8];
    const float* lw1  = (const float*)d_in[9];
    const float* lb1  = (const float*)d_in[10];
    const float* ow   = (const float*)d_in[11];
    const float* ob   = (const float*)d_in[12];
    int N  = in_sizes[0] / 3;
    int E  = in_sizes[3] / 2;
    int NE = in_sizes[4] / DF;   // 89 elements
    const int* src = ei;
    const int* dst = ei + E;

    char* ws = (char*)d_ws;
    size_t off = 0;
    auto alloc = [&](size_t bytes) { void* p = ws + off; off += (bytes + 255) / 256 * 256; return p; };

    float* tfe    = (float*)alloc((size_t)NE * DF * 4);
    float* u1     = (float*)alloc(DF * 4);
    float* vtmp   = (float*)alloc(DF * 4);
    float* wv0    = (float*)alloc(DF * 4);
    float* hb     = (float*)alloc(16 * 4);
    float* Gt     = (float*)alloc(16 * DF * 4);
    float* T      = (float*)alloc((size_t)NE * 256 * 4);
    float* t1     = (float*)alloc((size_t)NE * 16 * 4);
    float* hf     = (float*)alloc((size_t)NE * 16 * 4);
    float* embdot = (float*)alloc((size_t)NE * 4);
    float* yacc   = (float*)alloc((size_t)N * 16 * 4);

    float* out = (float*)d_out;

    int nyacc4 = (N * 64) / 16;
    int zblocks = (nyacc4 + 511) / 512;
    k_setup<<<128 + NE + zblocks, 512, 0, stream>>>(
        lw1, lw0, ow, emb, tw0, vtmp, wv0, tfe, (uint4*)yacc, nyacc4, out, NE);
    k_pre2<<<1, 512, 0, stream>>>(tw1, lb1, lb0, ow, ob, vtmp, u1, hb, out, N);
    k_gt_helem<<<32 + NE, 256, 0, stream>>>(lw0, u1, emb, ow, hb, Gt, hf, embdot);
    k_T<<<NE, 256, 0, stream>>>(tfe, Gt, wv0, T, t1);
    k_sh_yacc<<<(E + 255) / 256, 256, 0, stream>>>(pos, src, dst, cell, yacc, E);
    k_energy<<<(E + N + 255) / 256, 256, 0, stream>>>(
        pos, src, dst, an, cell, yacc, T, t1, hf, embdot, out, E, N);
}

// Round 11
// 60.111 us; speedup vs baseline: 4.6632x; 1.2672x over previous
//
#include <hip/hip_runtime.h>
#include <math.h>

#define DF 512
#define NEMAX 89
#define TPAD 264   // ushorts per padded T row (132 words, 132%32=4)
#define T1PAD 17

typedef __attribute__((ext_vector_type(8))) unsigned short ushort8;

__device__ __constant__ int c_lidx[16] = {0,1,1,1,2,2,2,2,2,3,3,3,3,3,3,3};

__device__ inline float bf2f(unsigned short s) {
    union { unsigned int u; float f; } x;
    x.u = ((unsigned int)s) << 16;
    return x.f;
}
__device__ inline unsigned short f2bf(float f) {
    union { float f; unsigned int u; } x; x.f = f;
    unsigned int r = x.u + 0x7fffu + ((x.u >> 16) & 1u);
    return (unsigned short)(r >> 16);
}

__device__ inline void sh_eval(float x, float y, float z, float* o)
{
    float x2 = x*x, y2 = y*y, z2 = z*z;
    o[0]  = 0.28209479177387814f;
    o[1]  = 0.4886025119029199f*y;
    o[2]  = 0.4886025119029199f*z;
    o[3]  = 0.4886025119029199f*x;
    o[4]  = 1.0925484305920792f*x*y;
    o[5]  = 1.0925484305920792f*y*z;
    o[6]  = 0.31539156525252005f*(3.0f*z2 - 1.0f);
    o[7]  = 1.0925484305920792f*x*z;
    o[8]  = 0.5462742152960396f*(x2 - y2);
    o[9]  = 0.5900435899266435f*y*(3.0f*x2 - y2);
    o[10] = 2.890611442640554f*x*y*z;
    o[11] = 0.4570457994644658f*y*(5.0f*z2 - 1.0f);
    o[12] = 0.3731763325901154f*z*(5.0f*z2 - 3.0f);
    o[13] = 0.4570457994644658f*x*(5.0f*z2 - 1.0f);
    o[14] = 1.445305721320277f*z*(x2 - y2);
    o[15] = 0.5900435899266435f*x*(x2 - 3.0f*y2);
}

__device__ inline void edge_dir(const float* __restrict__ pos, int s, int d,
                                float cx, float cy, float cz,
                                float& x, float& y, float& z)
{
    float ex = pos[d*3+0] - pos[s*3+0];
    float ey = pos[d*3+1] - pos[s*3+1];
    float ez = pos[d*3+2] - pos[s*3+2];
    ex -= rintf(ex/cx)*cx;
    ey -= rintf(ey/cy)*cy;
    ez -= rintf(ez/cz)*cz;
    float len = fmaxf(sqrtf(ex*ex + ey*ey + ez*ez), 1e-8f);
    x = ex/len; y = ey/len; z = ez/len;
}

// K_A: layered fused setup — blocks [0,64): vtmp=lw1@ow; [64,128): wv0=lw0@ow;
// [128,128+NE): tfe per element; rest: zero yacc (+ out)
__global__ __launch_bounds__(512) void k_setup(const float* __restrict__ lw1,
                                               const float* __restrict__ lw0,
                                               const float* __restrict__ ow,
                                               const float* __restrict__ emb,
                                               const float* __restrict__ tw0,
                                               float* __restrict__ vtmp,
                                               float* __restrict__ wv0,
                                               float* __restrict__ tfe,
                                               uint4* __restrict__ yacc4, int nyacc4,
                                               float* __restrict__ out, int NE)
{
    int b = blockIdx.x, t = threadIdx.x;
    if (b < 128) {
        const float* w = (b < 64) ? lw1 : lw0;
        float* v = (b < 64) ? vtmp : wv0;
        int bb = b & 63;
        int r = bb*8 + (t >> 6);
        int lane = t & 63;
        const float* row = w + (size_t)r * DF;
        float s = 0.0f;
        #pragma unroll
        for (int j = 0; j < 8; j++) s += row[lane + j*64] * ow[lane + j*64];
        #pragma unroll
        for (int off = 32; off > 0; off >>= 1) s += __shfl_xor(s, off, 64);
        if (lane == 0) v[r] = s;
    } else if (b < 128 + NE) {
        __shared__ float nf[DF];
        __shared__ float w[4*32*32];
        int a = b - 128;
        nf[t] = emb[(size_t)a*DF + t];
        for (int i = t; i < 4096; i += 512) w[i] = tw0[i];
        __syncthreads();
        int d = t >> 4, m = t & 15;
        int l = c_lidx[m];
        const float* wl = &w[l*1024 + d];
        float acc = 0.0f;
        #pragma unroll
        for (int c = 0; c < 32; c++) acc += nf[c*16 + m] * wl[c*32];
        tfe[(size_t)a*DF + t] = acc;
    } else {
        int i = (b - 128 - NE)*512 + t;
        if (i < nyacc4) yacc4[i] = make_uint4(0,0,0,0);
        if (i == 0) out[0] = 0.0f;
    }
}

// K_B: u1, hb, constant bias energy (1 block)
__global__ __launch_bounds__(512) void k_pre2(const float* __restrict__ tw1,
                                              const float* __restrict__ lb1,
                                              const float* __restrict__ lb0,
                                              const float* __restrict__ ow,
                                              const float* __restrict__ ob,
                                              const float* __restrict__ v,
                                              float* __restrict__ u1,
                                              float* __restrict__ hb,
                                              float* __restrict__ out, int N)
{
    __shared__ float vs[DF];
    __shared__ float red[DF];
    __shared__ float us[DF];
    int t = threadIdx.x;
    vs[t] = v[t];
    red[t] = (lb1[t] + lb0[t]) * ow[t];
    __syncthreads();
    int c = t >> 4, m = t & 15, l = c_lidx[m];
    float u = 0.0f;
    #pragma unroll
    for (int d = 0; d < 32; d++) u += tw1[l*1024 + c*32 + d] * vs[d*16 + m];
    u1[t] = u;
    us[t] = u;
    __syncthreads();
    for (int s = 256; s > 0; s >>= 1) {
        if (t < s) red[t] += red[t + s];
        __syncthreads();
    }
    if (t < 16) {
        float s = 0.0f;
        #pragma unroll
        for (int cc = 0; cc < 32; cc++) s += lb0[cc*16 + t] * us[cc*16 + t];
        hb[t] = s;
    }
    if (t == 0) atomicAdd(out, (float)N * (red[0] + ob[0]));
}

// K_C: blocks [0,32): Gt ; blocks [32,32+NE): helem
__global__ __launch_bounds__(256) void k_gt_helem(const float* __restrict__ lw0,
                                                  const float* __restrict__ u1,
                                                  const float* __restrict__ emb,
                                                  const float* __restrict__ ow,
                                                  const float* __restrict__ hb,
                                                  float* __restrict__ Gt,
                                                  float* __restrict__ hf,
                                                  float* __restrict__ embdot)
{
    int b = blockIdx.x, t = threadIdx.x;
    if (b < 32) {
        int g = b*256 + t;
        int k = g >> 4, m = g & 15;
        float s = 0.0f;
        #pragma unroll
        for (int c = 0; c < 32; c++) s += lw0[(size_t)k*DF + c*16 + m] * u1[c*16 + m];
        Gt[m*DF + k] = s;
    } else {
        __shared__ float r1[256];
        __shared__ float r2[DF];
        int a = b - 32;
        float e0 = emb[(size_t)a*DF + t];
        float e1 = emb[(size_t)a*DF + t + 256];
        r1[t] = e0*ow[t] + e1*ow[t+256];
        r2[t] = e0*u1[t];
        r2[t+256] = e1*u1[t+256];
        __syncthreads();
        for (int s = 128; s > 0; s >>= 1) {
            if (t < s) r1[t] += r1[t + s];
            __syncthreads();
        }
        if (t < 16) {
            float s = hb[t];
            #pragma unroll
            for (int c = 0; c < 32; c++) s += r2[c*16 + t];
            hf[(size_t)a*16 + t] = s;
        }
        if (t == 0) embdot[a] = r1[0];
    }
}

// K_D: Tbf[a][mm][m] (bf16) = sum_d tfe[a,d*16+mm]*Gt[m][d*16+mm]; t1[a][mm] f32
__global__ __launch_bounds__(256) void k_T(const float* __restrict__ tfe,
                                           const float* __restrict__ Gt,
                                           const float* __restrict__ wv0,
                                           unsigned short* __restrict__ Tbf,
                                           float* __restrict__ t1)
{
    __shared__ float tf_s[DF];
    int a = blockIdx.x, t = threadIdx.x;
    tf_s[t]       = tfe[(size_t)a*DF + t];
    tf_s[t + 256] = tfe[(size_t)a*DF + t + 256];
    __syncthreads();
    int mm = t >> 4, m = t & 15;
    float s = 0.0f;
    #pragma unroll
    for (int d = 0; d < 32; d++) s = fmaf(tf_s[d*16 + mm], Gt[m*DF + d*16 + mm], s);
    Tbf[(size_t)a*256 + mm*16 + m] = f2bf(s);
    if (t < 16) {
        float s1 = 0.0f;
        #pragma unroll
        for (int d = 0; d < 32; d++) s1 = fmaf(tf_s[d*16 + t], wv0[d*16 + t], s1);
        t1[(size_t)a*16 + t] = s1;
    }
}

// K_E: SH compute + yacc atomics, LDS-staged (no Y materialization).
__global__ __launch_bounds__(256) void k_sh_yacc(const float* __restrict__ pos,
                                                 const int* __restrict__ src,
                                                 const int* __restrict__ dst,
                                                 const float* __restrict__ cell,
                                                 float* __restrict__ yacc, int E)
{
    __shared__ float Yl[256][17];
    __shared__ int sAl[256];
    int b = blockIdx.x, t = threadIdx.x;
    int e = b*256 + t;
    float cx = cell[0], cy = cell[4], cz = cell[8];
    if (e < E) {
        int s = src[e], d = dst[e];
        float x, y, z;
        edge_dir(pos, s, d, cx, cy, cz, x, y, z);
        float o[16];
        sh_eval(x, y, z, o);
        #pragma unroll
        for (int j = 0; j < 16; j++) Yl[t][j] = o[j];
        sAl[t] = s;
    }
    __syncthreads();
    int lastvalid = min(256, E - b*256);
    #pragma unroll
    for (int j = 0; j < 16; j++) {
        int idx = j*256 + t;
        int el = idx >> 4, m = idx & 15;
        if (el < lastvalid)
            atomicAdd(&yacc[(size_t)sAl[el]*16 + m], Yl[el][m]);
    }
}

// K_F: edge-parallel energy; T staged in LDS as bf16 (padded rows), t1 in LDS.
__global__ __launch_bounds__(256) void k_energy(const float* __restrict__ pos,
                                                const int* __restrict__ src,
                                                const int* __restrict__ dst,
                                                const int* __restrict__ an,
                                                const float* __restrict__ cell,
                                                const float* __restrict__ yacc,
                                                const unsigned short* __restrict__ Tbf,
                                                const float* __restrict__ t1,
                                                const float* __restrict__ hf,
                                                const float* __restrict__ embdot,
                                                float* __restrict__ out,
                                                int E, int N, int NE)
{
    __shared__ __align__(16) unsigned short Ts[NEMAX * TPAD];  // 46,992 B
    __shared__ float t1s[NEMAX * T1PAD];                        // 6,052 B
    __shared__ float wred[4];
    int t = threadIdx.x;
    // stage Tbf -> Ts (16B chunks, coalesced global reads, aligned LDS writes)
    int nchunk = NE * 32;   // 32 chunks of 8 ushorts per row
    for (int c = t; c < nchunk; c += 256) {
        int a = c >> 5, k = c & 31;
        *(ushort8*)&Ts[a*TPAD + k*8] = *(const ushort8*)&Tbf[(size_t)a*256 + k*8];
    }
    for (int i = t; i < NE*16; i += 256) {
        int a = i >> 4, mm = i & 15;
        t1s[a*T1PAD + mm] = t1[i];
    }
    __syncthreads();

    int i = blockIdx.x * 256 + t;
    float s = 0.0f;
    if (i < E) {
        int sn = src[i], d = dst[i];
        int a = an[sn];
        float x, y, z;
        edge_dir(pos, sn, d, cell[0], cell[4], cell[8], x, y, z);
        float ov[16];
        sh_eval(x, y, z, ov);
        const float4* dp = (const float4*)(yacc + (size_t)d*16);
        float4 D0 = dp[0], D1 = dp[1], D2 = dp[2], D3 = dp[3];
        const unsigned short* Ta = &Ts[a * TPAD];
        const float* ta1 = &t1s[a * T1PAD];
        #pragma unroll
        for (int mm = 0; mm < 16; mm++) {
            ushort8 p0 = *(const ushort8*)&Ta[mm*16];
            ushort8 p1 = *(const ushort8*)&Ta[mm*16 + 8];
            float dotv = bf2f(p0[0])*D0.x + bf2f(p0[1])*D0.y + bf2f(p0[2])*D0.z + bf2f(p0[3])*D0.w
                       + bf2f(p0[4])*D1.x + bf2f(p0[5])*D1.y + bf2f(p0[6])*D1.z + bf2f(p0[7])*D1.w
                       + bf2f(p1[0])*D2.x + bf2f(p1[1])*D2.y + bf2f(p1[2])*D2.z + bf2f(p1[3])*D2.w
                       + bf2f(p1[4])*D3.x + bf2f(p1[5])*D3.y + bf2f(p1[6])*D3.z + bf2f(p1[7])*D3.w;
            s = fmaf(ov[mm], dotv + ta1[mm], s);
        }
    } else if (i < E + N) {
        int n = i - E;
        int a = an[n];
        const float4* hp = (const float4*)(hf + (size_t)a*16);
        float4 H0 = hp[0], H1 = hp[1], H2 = hp[2], H3 = hp[3];
        const float4* vp = (const float4*)(yacc + (size_t)n*16);
        float4 V0 = vp[0], V1 = vp[1], V2 = vp[2], V3 = vp[3];
        s = embdot[a]
          + H0.x*V0.x + H0.y*V0.y + H0.z*V0.z + H0.w*V0.w
          + H1.x*V1.x + H1.y*V1.y + H1.z*V1.z + H1.w*V1.w
          + H2.x*V2.x + H2.y*V2.y + H2.z*V2.z + H2.w*V2.w
          + H3.x*V3.x + H3.y*V3.y + H3.z*V3.z + H3.w*V3.w;
    }
    #pragma unroll
    for (int off = 32; off > 0; off >>= 1) s += __shfl_xor(s, off, 64);
    int lane = t & 63, w = t >> 6;
    if (lane == 0) wred[w] = s;
    __syncthreads();
    if (t == 0) atomicAdd(out, wred[0] + wred[1] + wred[2] + wred[3]);
}

extern "C" void kernel_launch(void* const* d_in, const int* in_sizes, int n_in,
                              void* d_out, int out_size, void* d_ws, size_t ws_size,
                              hipStream_t stream)
{
    const float* pos  = (const float*)d_in[0];
    const float* cell = (const float*)d_in[1];
    const int*   an   = (const int*)d_in[2];
    const int*   ei   = (const int*)d_in[3];
    const float* emb  = (const float*)d_in[4];
    const float* tw0  = (const float*)d_in[5];
    const float* lw0  = (const float*)d_in[6];
    const float* lb0  = (const float*)d_in[7];
    const float* tw1  = (const float*)d_in[8];
    const float* lw1  = (const float*)d_in[9];
    const float* lb1  = (const float*)d_in[10];
    const float* ow   = (const float*)d_in[11];
    const float* ob   = (const float*)d_in[12];
    int N  = in_sizes[0] / 3;
    int E  = in_sizes[3] / 2;
    int NE = in_sizes[4] / DF;   // 89 elements
    const int* src = ei;
    const int* dst = ei + E;

    char* ws = (char*)d_ws;
    size_t off = 0;
    auto alloc = [&](size_t bytes) { void* p = ws + off; off += (bytes + 255) / 256 * 256; return p; };

    float* tfe    = (float*)alloc((size_t)NE * DF * 4);
    float* u1     = (float*)alloc(DF * 4);
    float* vtmp   = (float*)alloc(DF * 4);
    float* wv0    = (float*)alloc(DF * 4);
    float* hb     = (float*)alloc(16 * 4);
    float* Gt     = (float*)alloc(16 * DF * 4);
    unsigned short* Tbf = (unsigned short*)alloc((size_t)NE * 256 * 2);
    float* t1     = (float*)alloc((size_t)NE * 16 * 4);
    float* hf     = (float*)alloc((size_t)NE * 16 * 4);
    float* embdot = (float*)alloc((size_t)NE * 4);
    float* yacc   = (float*)alloc((size_t)N * 16 * 4);

    float* out = (float*)d_out;

    int nyacc4 = (N * 64) / 16;
    int zblocks = (nyacc4 + 511) / 512;
    k_setup<<<128 + NE + zblocks, 512, 0, stream>>>(
        lw1, lw0, ow, emb, tw0, vtmp, wv0, tfe, (uint4*)yacc, nyacc4, out, NE);
    k_pre2<<<1, 512, 0, stream>>>(tw1, lb1, lb0, ow, ob, vtmp, u1, hb, out, N);
    k_gt_helem<<<32 + NE, 256, 0, stream>>>(lw0, u1, emb, ow, hb, Gt, hf, embdot);
    k_T<<<NE, 256, 0, stream>>>(tfe, Gt, wv0, Tbf, t1);
    k_sh_yacc<<<(E + 255) / 256, 256, 0, stream>>>(pos, src, dst, cell, yacc, E);
    k_energy<<<(E + N + 255) / 256, 256, 0, stream>>>(
        pos, src, dst, an, cell, yacc, Tbf, t1, hf, embdot, out, E, N, NE);
}